// Round 1
// baseline (232.221 us; speedup 1.0000x reference)
//
#include <hip/hip_runtime.h>
#include <hip/hip_bf16.h>
#include <type_traits>

// Problem constants (from reference)
#define BATCH_N   16384
#define FEAT      128      // MOVIE_FEAT == USER_FEAT
#define NNBR      50

typedef short  short8  __attribute__((ext_vector_type(8)));
typedef float  floatx4 __attribute__((ext_vector_type(4)));

__device__ __forceinline__ __hip_bfloat16 f2bf(float x) { return __float2bfloat16(x); }

// ---------------------------------------------------------------------------
// prep: build bf16 transposed weights  Wt[n][k]  (K-contiguous rows so both
// MFMA A and B fragments are ds_read_b128-able) + fused bias bu+bm.
// WcatT = [Wu; Wm]^T as [256(n)][256(k)]; W1T [256][256]; W2T [128][256];
// WmT [256(n)][128(k)].
// ---------------------------------------------------------------------------
__global__ __launch_bounds__(256) void prep_kernel(
    const float* __restrict__ Wu, const float* __restrict__ Wm,
    const float* __restrict__ W1, const float* __restrict__ W2,
    const float* __restrict__ bu, const float* __restrict__ bm,
    __hip_bfloat16* __restrict__ WcatT, __hip_bfloat16* __restrict__ WmT,
    __hip_bfloat16* __restrict__ W1T,  __hip_bfloat16* __restrict__ W2T,
    float* __restrict__ bc) {
  int idx = blockIdx.x * 256 + threadIdx.x;   // 0..65535
  int n = idx & 255, k = idx >> 8;            // reads coalesced over n
  float v = (k < 128) ? Wu[k * 256 + n] : Wm[(k - 128) * 256 + n];
  WcatT[n * 256 + k] = f2bf(v);
  W1T[n * 256 + k]   = f2bf(W1[k * 256 + n]);
  if (k < 128) WmT[n * 128 + k] = f2bf(Wm[k * 256 + n]);
  if (idx < 32768) {
    int k2 = idx >> 7, n2 = idx & 127;
    W2T[n2 * 256 + k2] = f2bf(W2[k2 * 128 + n2]);
  }
  if (idx < 256) bc[idx] = bu[idx] + bm[idx];
}

// ---------------------------------------------------------------------------
// gather_user: one wave per batch row.
// A_user[b] = [ users[b] (128) | (1/50) * sum_j movie_table[nbr_ids[b][j]] ]
// lane l covers feature dims {2l, 2l+1} (float2 per lane = coalesced 512B/row)
// ---------------------------------------------------------------------------
__global__ __launch_bounds__(256) void gather_user(
    const float* __restrict__ users, const int* __restrict__ nbr_ids,
    const float* __restrict__ table, __hip_bfloat16* __restrict__ A_user) {
  int row  = (blockIdx.x << 2) + (threadIdx.x >> 6);
  int lane = threadIdx.x & 63;
  const int* nb = nbr_ids + row * NNBR;
  float ax = 0.f, ay = 0.f;
  #pragma unroll 5
  for (int j = 0; j < NNBR; ++j) {
    int id = nb[j];
    float2 v = ((const float2*)(table + (size_t)id * FEAT))[lane];
    ax += v.x; ay += v.y;
  }
  ax *= (1.f / NNBR); ay *= (1.f / NNBR);
  float2 uv = ((const float2*)(users + (size_t)row * FEAT))[lane];
  __hip_bfloat162* dst = (__hip_bfloat162*)(A_user + (size_t)row * (2 * FEAT));
  __hip_bfloat162 t0; t0.x = f2bf(uv.x); t0.y = f2bf(uv.y);
  __hip_bfloat162 t1; t1.x = f2bf(ax);   t1.y = f2bf(ay);
  dst[lane]      = t0;
  dst[64 + lane] = t1;
}

// ---------------------------------------------------------------------------
// gather_pn: one wave per row; rows [0,B) = pos ids, [B,2B) = neg ids.
// A_pn[r] = movie_table[id] (128 floats -> bf16)
// ---------------------------------------------------------------------------
__global__ __launch_bounds__(256) void gather_pn(
    const int* __restrict__ pos_ids, const int* __restrict__ neg_ids,
    const float* __restrict__ table, __hip_bfloat16* __restrict__ A_pn) {
  int row  = (blockIdx.x << 2) + (threadIdx.x >> 6);
  int lane = threadIdx.x & 63;
  int id = (row < BATCH_N) ? pos_ids[row] : neg_ids[row - BATCH_N];
  float2 v = ((const float2*)(table + (size_t)id * FEAT))[lane];
  __hip_bfloat162 t; t.x = f2bf(v.x); t.y = f2bf(v.y);
  ((__hip_bfloat162*)(A_pn + (size_t)row * FEAT))[lane] = t;
}

// ---------------------------------------------------------------------------
// gemm_bf16: C[M][NDIM] = act(A[M][KDIM] @ Wt^T + bias)
//   A row-major [M][K] bf16, Wt row-major [N][K] bf16 (pre-transposed).
//   Tile: BM=128, BN=128, BK=32. 4 waves in 2x2; each wave 64x64 via 4x4
//   grid of 16x16x32 MFMAs. M, N, K all multiples of tile dims (no guards).
// MFMA layouts (guide-verified):
//   A frag lane l elem j: A[m = l&15][k = (l>>4)*8 + j]
//   B frag lane l elem j: B[k = (l>>4)*8 + j][n = l&15]  == Wt[l&15][...]
//   C/D:   lane l reg r -> row = (l>>4)*4 + r, col = l&15
// ---------------------------------------------------------------------------
template <int KDIM, int NDIM, bool RELU, typename OutT>
__global__ __launch_bounds__(256) void gemm_bf16(
    const __hip_bfloat16* __restrict__ A, const __hip_bfloat16* __restrict__ Wt,
    const float* __restrict__ bias, OutT* __restrict__ C) {
  __shared__ __hip_bfloat16 Al[128][40];   // +8 bf16 pad per row (bank spread)
  __shared__ __hip_bfloat16 Bl[128][40];

  const int t    = threadIdx.x;
  const int lane = t & 63;
  const int wid  = t >> 6;
  const int wm   = wid & 1, wn = wid >> 1;
  const int quad = lane >> 4, lrow = lane & 15;
  const long m0  = (long)blockIdx.x * 128;
  const int  n0  = blockIdx.y * 128;

  const int c0 = t, c1 = t + 256;          // 512 chunks of 8 bf16 per tile
  const int r0 = c0 >> 2, kc0 = (c0 & 3) * 8;
  const int r1 = c1 >> 2, kc1 = (c1 & 3) * 8;

  floatx4 acc[4][4] = {};

  for (int k0 = 0; k0 < KDIM; k0 += 32) {
    short8 a0 = *(const short8*)(A  + (m0 + r0) * KDIM + k0 + kc0);
    short8 a1 = *(const short8*)(A  + (m0 + r1) * KDIM + k0 + kc1);
    short8 b0 = *(const short8*)(Wt + (long)(n0 + r0) * KDIM + k0 + kc0);
    short8 b1 = *(const short8*)(Wt + (long)(n0 + r1) * KDIM + k0 + kc1);
    __syncthreads();                       // prev-iter frag reads done
    *(short8*)&Al[r0][kc0] = a0;
    *(short8*)&Al[r1][kc1] = a1;
    *(short8*)&Bl[r0][kc0] = b0;
    *(short8*)&Bl[r1][kc1] = b1;
    __syncthreads();

    short8 af[4], bfr[4];
    #pragma unroll
    for (int i = 0; i < 4; ++i)
      af[i] = *(const short8*)&Al[wm * 64 + i * 16 + lrow][quad * 8];
    #pragma unroll
    for (int i = 0; i < 4; ++i)
      bfr[i] = *(const short8*)&Bl[wn * 64 + i * 16 + lrow][quad * 8];

    #pragma unroll
    for (int i = 0; i < 4; ++i)
      #pragma unroll
      for (int j = 0; j < 4; ++j)
        acc[i][j] = __builtin_amdgcn_mfma_f32_16x16x32_bf16(
            af[i], bfr[j], acc[i][j], 0, 0, 0);
  }

  #pragma unroll
  for (int i = 0; i < 4; ++i) {
    #pragma unroll
    for (int j = 0; j < 4; ++j) {
      int gcol = n0 + wn * 64 + j * 16 + lrow;
      float bv = bias[gcol];
      #pragma unroll
      for (int r = 0; r < 4; ++r) {
        long grow = m0 + wm * 64 + i * 16 + quad * 4 + r;
        float v = acc[i][j][r] + bv;
        if (RELU) v = fmaxf(v, 0.f);
        if constexpr (std::is_same<OutT, float>::value)
          C[grow * NDIM + gcol] = v;
        else
          C[grow * NDIM + gcol] = f2bf(v);
      }
    }
  }
}

// ---------------------------------------------------------------------------
extern "C" void kernel_launch(void* const* d_in, const int* in_sizes, int n_in,
                              void* d_out, int out_size, void* d_ws, size_t ws_size,
                              hipStream_t stream) {
  const float* users   = (const float*)d_in[0];
  // d_in[1] pos_movies, d_in[2] neg_movies, d_in[3] user_ids: unused by ref
  const int*   pos_ids = (const int*)d_in[4];
  const int*   neg_ids = (const int*)d_in[5];
  const int*   nbr_ids = (const int*)d_in[6];
  const float* table   = (const float*)d_in[7];
  const float* Wu = (const float*)d_in[8];
  const float* bu = (const float*)d_in[9];
  const float* Wm = (const float*)d_in[10];
  const float* bm = (const float*)d_in[11];
  const float* W1 = (const float*)d_in[12];
  const float* b1 = (const float*)d_in[13];
  const float* W2 = (const float*)d_in[14];
  const float* b2 = (const float*)d_in[15];
  float* out = (float*)d_out;

  // workspace carve (all 256B aligned). Total ~67.6 MB.
  char* p = (char*)d_ws;
  auto carve = [&](size_t bytes) { char* r = p; p += (bytes + 255) & ~(size_t)255; return r; };
  __hip_bfloat16* WcatT  = (__hip_bfloat16*)carve(256 * 256 * 2);
  __hip_bfloat16* WmT    = (__hip_bfloat16*)carve(256 * 128 * 2);
  __hip_bfloat16* W1T    = (__hip_bfloat16*)carve(256 * 256 * 2);
  __hip_bfloat16* W2T    = (__hip_bfloat16*)carve(128 * 256 * 2);
  float*          bc     = (float*)carve(256 * 4);
  __hip_bfloat16* A_user = (__hip_bfloat16*)carve((size_t)BATCH_N * 256 * 2);
  __hip_bfloat16* A_pn   = (__hip_bfloat16*)carve((size_t)2 * BATCH_N * 128 * 2);
  __hip_bfloat16* E      = (__hip_bfloat16*)carve((size_t)3 * BATCH_N * 256 * 2);
  __hip_bfloat16* H      = (__hip_bfloat16*)carve((size_t)3 * BATCH_N * 256 * 2);

  prep_kernel<<<256, 256, 0, stream>>>(Wu, Wm, W1, W2, bu, bm,
                                       WcatT, WmT, W1T, W2T, bc);
  gather_user<<<BATCH_N / 4, 256, 0, stream>>>(users, nbr_ids, table, A_user);
  gather_pn<<<2 * BATCH_N / 4, 256, 0, stream>>>(pos_ids, neg_ids, table, A_pn);

  // E rows: [0,B) user | [B,2B) pos | [2B,3B) neg
  gemm_bf16<256, 256, false, __hip_bfloat16>
      <<<dim3(BATCH_N / 128, 2), 256, 0, stream>>>(A_user, WcatT, bc, E);
  gemm_bf16<128, 256, false, __hip_bfloat16>
      <<<dim3(2 * BATCH_N / 128, 2), 256, 0, stream>>>(A_pn, WmT, bm,
                                                       E + (size_t)BATCH_N * 256);
  gemm_bf16<256, 256, true, __hip_bfloat16>
      <<<dim3(3 * BATCH_N / 128, 2), 256, 0, stream>>>(E, W1T, b1, H);
  gemm_bf16<256, 128, true, float>
      <<<dim3(3 * BATCH_N / 128, 1), 256, 0, stream>>>(H, W2T, b2, out);
}

// Round 2
// 218.318 us; speedup vs baseline: 1.0637x; 1.0637x over previous
//
#include <hip/hip_runtime.h>
#include <hip/hip_bf16.h>
#include <type_traits>

// Problem constants (from reference)
#define BATCH_N   16384
#define FEAT      128      // MOVIE_FEAT == USER_FEAT
#define NNBR      50
#define NUM_MOVIES_N 100000

typedef short  short8  __attribute__((ext_vector_type(8)));
typedef float  floatx4 __attribute__((ext_vector_type(4)));

__device__ __forceinline__ __hip_bfloat16 f2bf(float x) { return __float2bfloat16(x); }

// ---------------------------------------------------------------------------
// conv_table: fp32 movie_table -> bf16 copy (25 MB, L2/L3-resident for gathers)
// 12.8M elements, 8 per thread, 16B stores.
// ---------------------------------------------------------------------------
__global__ __launch_bounds__(256) void conv_table(
    const float* __restrict__ t, __hip_bfloat16* __restrict__ tb) {
  size_t i = ((size_t)blockIdx.x * 256 + threadIdx.x) * 8;
  float4 v0 = *(const float4*)(t + i);
  float4 v1 = *(const float4*)(t + i + 4);
  __hip_bfloat16 o[8];
  o[0] = f2bf(v0.x); o[1] = f2bf(v0.y); o[2] = f2bf(v0.z); o[3] = f2bf(v0.w);
  o[4] = f2bf(v1.x); o[5] = f2bf(v1.y); o[6] = f2bf(v1.z); o[7] = f2bf(v1.w);
  *(short8*)(tb + i) = *(short8*)o;
}

// ---------------------------------------------------------------------------
// prep: build bf16 transposed weights  Wt[n][k] + fused bias bu+bm.
// ---------------------------------------------------------------------------
__global__ __launch_bounds__(256) void prep_kernel(
    const float* __restrict__ Wu, const float* __restrict__ Wm,
    const float* __restrict__ W1, const float* __restrict__ W2,
    const float* __restrict__ bu, const float* __restrict__ bm,
    __hip_bfloat16* __restrict__ WcatT, __hip_bfloat16* __restrict__ WmT,
    __hip_bfloat16* __restrict__ W1T,  __hip_bfloat16* __restrict__ W2T,
    float* __restrict__ bc) {
  int idx = blockIdx.x * 256 + threadIdx.x;   // 0..65535
  int n = idx & 255, k = idx >> 8;            // reads coalesced over n
  float v = (k < 128) ? Wu[k * 256 + n] : Wm[(k - 128) * 256 + n];
  WcatT[n * 256 + k] = f2bf(v);
  W1T[n * 256 + k]   = f2bf(W1[k * 256 + n]);
  if (k < 128) WmT[n * 128 + k] = f2bf(Wm[k * 256 + n]);
  if (idx < 32768) {
    int k2 = idx >> 7, n2 = idx & 127;
    W2T[n2 * 256 + k2] = f2bf(W2[k2 * 128 + n2]);
  }
  if (idx < 256) bc[idx] = bu[idx] + bm[idx];
}

// ---------------------------------------------------------------------------
// gather_user: one wave per batch row, bf16 table (256 B/row).
// A_user[b] = [ users[b] (128, fp32->bf16) | (1/50)*sum_j tb[nbr_ids[b][j]] ]
// lane l covers feature dims {2l, 2l+1}: bf16x2 (4 B) per lane per row.
// ---------------------------------------------------------------------------
__global__ __launch_bounds__(256) void gather_user(
    const float* __restrict__ users, const int* __restrict__ nbr_ids,
    const __hip_bfloat16* __restrict__ tb, __hip_bfloat16* __restrict__ A_user) {
  int row  = (blockIdx.x << 2) + (threadIdx.x >> 6);
  int lane = threadIdx.x & 63;
  const int* nb = nbr_ids + row * NNBR;
  float ax = 0.f, ay = 0.f;
  #pragma unroll 5
  for (int j = 0; j < NNBR; ++j) {
    int id = nb[j];
    __hip_bfloat162 v = ((const __hip_bfloat162*)(tb + (size_t)id * FEAT))[lane];
    ax += __bfloat162float(v.x); ay += __bfloat162float(v.y);
  }
  ax *= (1.f / NNBR); ay *= (1.f / NNBR);
  float2 uv = ((const float2*)(users + (size_t)row * FEAT))[lane];
  __hip_bfloat162* dst = (__hip_bfloat162*)(A_user + (size_t)row * (2 * FEAT));
  __hip_bfloat162 t0; t0.x = f2bf(uv.x); t0.y = f2bf(uv.y);
  __hip_bfloat162 t1; t1.x = f2bf(ax);   t1.y = f2bf(ay);
  dst[lane]      = t0;
  dst[64 + lane] = t1;
}

// ---------------------------------------------------------------------------
// gather_pn: one wave per row; rows [0,B) = pos ids, [B,2B) = neg ids.
// Pure bf16 row copy from tb (no conversion).
// ---------------------------------------------------------------------------
__global__ __launch_bounds__(256) void gather_pn(
    const int* __restrict__ pos_ids, const int* __restrict__ neg_ids,
    const __hip_bfloat16* __restrict__ tb, __hip_bfloat16* __restrict__ A_pn) {
  int row  = (blockIdx.x << 2) + (threadIdx.x >> 6);
  int lane = threadIdx.x & 63;
  int id = (row < BATCH_N) ? pos_ids[row] : neg_ids[row - BATCH_N];
  __hip_bfloat162 v = ((const __hip_bfloat162*)(tb + (size_t)id * FEAT))[lane];
  ((__hip_bfloat162*)(A_pn + (size_t)row * FEAT))[lane] = v;
}

// ---------------------------------------------------------------------------
// gemm_bf16: C[M][NDIM] = act(A[M][KDIM] @ Wt^T + bias)
//   A row-major [M][K] bf16, Wt row-major [N][K] bf16 (pre-transposed).
//   Tile: BM=128, BN=128, BK=32. 4 waves in 2x2; each wave 64x64 via 4x4
//   grid of 16x16x32 MFMAs.
// ---------------------------------------------------------------------------
template <int KDIM, int NDIM, bool RELU, typename OutT>
__global__ __launch_bounds__(256) void gemm_bf16(
    const __hip_bfloat16* __restrict__ A, const __hip_bfloat16* __restrict__ Wt,
    const float* __restrict__ bias, OutT* __restrict__ C) {
  __shared__ __hip_bfloat16 Al[128][40];   // +8 bf16 pad per row (bank spread)
  __shared__ __hip_bfloat16 Bl[128][40];

  const int t    = threadIdx.x;
  const int lane = t & 63;
  const int wid  = t >> 6;
  const int wm   = wid & 1, wn = wid >> 1;
  const int quad = lane >> 4, lrow = lane & 15;
  const long m0  = (long)blockIdx.x * 128;
  const int  n0  = blockIdx.y * 128;

  const int c0 = t, c1 = t + 256;          // 512 chunks of 8 bf16 per tile
  const int r0 = c0 >> 2, kc0 = (c0 & 3) * 8;
  const int r1 = c1 >> 2, kc1 = (c1 & 3) * 8;

  floatx4 acc[4][4] = {};

  for (int k0 = 0; k0 < KDIM; k0 += 32) {
    short8 a0 = *(const short8*)(A  + (m0 + r0) * KDIM + k0 + kc0);
    short8 a1 = *(const short8*)(A  + (m0 + r1) * KDIM + k0 + kc1);
    short8 b0 = *(const short8*)(Wt + (long)(n0 + r0) * KDIM + k0 + kc0);
    short8 b1 = *(const short8*)(Wt + (long)(n0 + r1) * KDIM + k0 + kc1);
    __syncthreads();                       // prev-iter frag reads done
    *(short8*)&Al[r0][kc0] = a0;
    *(short8*)&Al[r1][kc1] = a1;
    *(short8*)&Bl[r0][kc0] = b0;
    *(short8*)&Bl[r1][kc1] = b1;
    __syncthreads();

    short8 af[4], bfr[4];
    #pragma unroll
    for (int i = 0; i < 4; ++i)
      af[i] = *(const short8*)&Al[wm * 64 + i * 16 + lrow][quad * 8];
    #pragma unroll
    for (int i = 0; i < 4; ++i)
      bfr[i] = *(const short8*)&Bl[wn * 64 + i * 16 + lrow][quad * 8];

    #pragma unroll
    for (int i = 0; i < 4; ++i)
      #pragma unroll
      for (int j = 0; j < 4; ++j)
        acc[i][j] = __builtin_amdgcn_mfma_f32_16x16x32_bf16(
            af[i], bfr[j], acc[i][j], 0, 0, 0);
  }

  #pragma unroll
  for (int i = 0; i < 4; ++i) {
    #pragma unroll
    for (int j = 0; j < 4; ++j) {
      int gcol = n0 + wn * 64 + j * 16 + lrow;
      float bv = bias[gcol];
      #pragma unroll
      for (int r = 0; r < 4; ++r) {
        long grow = m0 + wm * 64 + i * 16 + quad * 4 + r;
        float v = acc[i][j][r] + bv;
        if (RELU) v = fmaxf(v, 0.f);
        if constexpr (std::is_same<OutT, float>::value)
          C[grow * NDIM + gcol] = v;
        else
          C[grow * NDIM + gcol] = f2bf(v);
      }
    }
  }
}

// ---------------------------------------------------------------------------
extern "C" void kernel_launch(void* const* d_in, const int* in_sizes, int n_in,
                              void* d_out, int out_size, void* d_ws, size_t ws_size,
                              hipStream_t stream) {
  const float* users   = (const float*)d_in[0];
  // d_in[1] pos_movies, d_in[2] neg_movies, d_in[3] user_ids: unused by ref
  const int*   pos_ids = (const int*)d_in[4];
  const int*   neg_ids = (const int*)d_in[5];
  const int*   nbr_ids = (const int*)d_in[6];
  const float* table   = (const float*)d_in[7];
  const float* Wu = (const float*)d_in[8];
  const float* bu = (const float*)d_in[9];
  const float* Wm = (const float*)d_in[10];
  const float* bm = (const float*)d_in[11];
  const float* W1 = (const float*)d_in[12];
  const float* b1 = (const float*)d_in[13];
  const float* W2 = (const float*)d_in[14];
  const float* b2 = (const float*)d_in[15];
  float* out = (float*)d_out;

  // workspace carve (all 256B aligned). Total ~93 MB.
  char* p = (char*)d_ws;
  auto carve = [&](size_t bytes) { char* r = p; p += (bytes + 255) & ~(size_t)255; return r; };
  __hip_bfloat16* tb     = (__hip_bfloat16*)carve((size_t)NUM_MOVIES_N * FEAT * 2);
  __hip_bfloat16* WcatT  = (__hip_bfloat16*)carve(256 * 256 * 2);
  __hip_bfloat16* WmT    = (__hip_bfloat16*)carve(256 * 128 * 2);
  __hip_bfloat16* W1T    = (__hip_bfloat16*)carve(256 * 256 * 2);
  __hip_bfloat16* W2T    = (__hip_bfloat16*)carve(128 * 256 * 2);
  float*          bc     = (float*)carve(256 * 4);
  __hip_bfloat16* A_user = (__hip_bfloat16*)carve((size_t)BATCH_N * 256 * 2);
  __hip_bfloat16* A_pn   = (__hip_bfloat16*)carve((size_t)2 * BATCH_N * 128 * 2);
  __hip_bfloat16* E      = (__hip_bfloat16*)carve((size_t)3 * BATCH_N * 256 * 2);
  __hip_bfloat16* H      = (__hip_bfloat16*)carve((size_t)3 * BATCH_N * 256 * 2);

  // 100000*128/8 = 1.6M threads -> 6250 blocks
  conv_table<<<NUM_MOVIES_N * FEAT / (256 * 8), 256, 0, stream>>>(table, tb);
  prep_kernel<<<256, 256, 0, stream>>>(Wu, Wm, W1, W2, bu, bm,
                                       WcatT, WmT, W1T, W2T, bc);
  gather_user<<<BATCH_N / 4, 256, 0, stream>>>(users, nbr_ids, tb, A_user);
  gather_pn<<<2 * BATCH_N / 4, 256, 0, stream>>>(pos_ids, neg_ids, tb, A_pn);

  // E rows: [0,B) user | [B,2B) pos | [2B,3B) neg
  gemm_bf16<256, 256, false, __hip_bfloat16>
      <<<dim3(BATCH_N / 128, 2), 256, 0, stream>>>(A_user, WcatT, bc, E);
  gemm_bf16<128, 256, false, __hip_bfloat16>
      <<<dim3(2 * BATCH_N / 128, 2), 256, 0, stream>>>(A_pn, WmT, bm,
                                                       E + (size_t)BATCH_N * 256);
  gemm_bf16<256, 256, true, __hip_bfloat16>
      <<<dim3(3 * BATCH_N / 128, 2), 256, 0, stream>>>(E, W1T, b1, H);
  gemm_bf16<256, 128, true, float>
      <<<dim3(3 * BATCH_N / 128, 1), 256, 0, stream>>>(H, W2T, b2, out);
}